// Round 2
// 978.974 us; speedup vs baseline: 1.1237x; 1.1237x over previous
//
#include <hip/hip_runtime.h>
#include <math.h>

// Problem constants (fixed by the reference)
#define B_SZ 2
#define L_SEQ 4096
#define D_MODEL 1024
#define D_INNER 2048
#define D_STATE 64
#define DT_RANK 128
#define BL (B_SZ * L_SEQ)          // 8192 tokens

#define AS1 __attribute__((address_space(1)))
#define AS3 __attribute__((address_space(3)))

typedef __attribute__((ext_vector_type(8))) short bf16x8_t;  // 8 bf16 = 4 VGPRs
typedef __attribute__((ext_vector_type(4))) float f32x4_t;

__device__ __forceinline__ unsigned short f2bf(float f) {
    unsigned int u = __float_as_uint(f);
    u = (u + 0x7FFFu + ((u >> 16) & 1u)) >> 16;   // RNE
    return (unsigned short)u;
}
__device__ __forceinline__ float bf2f(unsigned short h) {
    return __uint_as_float(((unsigned int)h) << 16);
}

// ---------------------------------------------------------------------------
// fp32 -> bf16 bulk convert (n4 = count of float4 groups)
// ---------------------------------------------------------------------------
__global__ __launch_bounds__(256) void cvt_f32_bf16(
    const float* __restrict__ in, unsigned short* __restrict__ out, int n4)
{
    int i = blockIdx.x * 256 + threadIdx.x;
    if (i >= n4) return;
    float4 v = ((const float4*)in)[i];
    ushort4 o;
    o.x = f2bf(v.x); o.y = f2bf(v.y); o.z = f2bf(v.z); o.w = f2bf(v.w);
    ((ushort4*)out)[i] = o;
}

// xdbl[:, :128] (fp32, row stride 256) -> packed bf16 [8192][128]
__global__ __launch_bounds__(256) void cvt_dtpart(
    const float* __restrict__ xdbl, unsigned short* __restrict__ out)
{
    int i = blockIdx.x * 256 + threadIdx.x;   // 0 .. 8192*32-1
    int m = i >> 5, c = i & 31;
    float4 v = *(const float4*)(xdbl + (size_t)m * 256 + c * 4);
    ushort4 o;
    o.x = f2bf(v.x); o.y = f2bf(v.y); o.z = f2bf(v.z); o.w = f2bf(v.w);
    ((ushort4*)(out))[(size_t)m * 32 + c] = o;
}

// ---------------------------------------------------------------------------
// bf16 MFMA GEMM: C[m][n] = act( sum_k A[m][k]*B[n][k] [+ bias[m]] )
// A: M x K bf16 row-major (lda), B: N x K bf16 row-major (ldb), C fp32 (ldc).
// act: 0 none, 1 softplus with bias indexed by ROW m, 2 silu.
// Tile 128x128, BK=32, 256 threads = 4 waves (2x2 of 64x64 per wave).
// ---------------------------------------------------------------------------
__global__ __launch_bounds__(256) void gemm_bf16(
    const unsigned short* __restrict__ A, int lda,
    const unsigned short* __restrict__ B, int ldb,
    float* __restrict__ C, int ldc, int K,
    const float* __restrict__ bias, int act)
{
    __shared__ unsigned short As[128 * 32];   // [row][k] linear, no pad
    __shared__ unsigned short Bs[128 * 32];

    const int tid = threadIdx.x;
    const int w = tid >> 6, lane = tid & 63;
    const int bm = blockIdx.y * 128, bn = blockIdx.x * 128;
    const int wm = (w & 1) * 64, wn = (w >> 1) * 64;

    f32x4_t acc[4][4];
#pragma unroll
    for (int i = 0; i < 4; ++i)
#pragma unroll
        for (int j = 0; j < 4; ++j) acc[i][j] = (f32x4_t){0.f, 0.f, 0.f, 0.f};

    const int srow = lane >> 2;
    const int scol = (lane & 3) * 8;
    const unsigned short* Ag0 = A + (size_t)(bm + w * 16 + srow) * lda + scol;
    const unsigned short* Ag1 = A + (size_t)(bm + 64 + w * 16 + srow) * lda + scol;
    const unsigned short* Bg0 = B + (size_t)(bn + w * 16 + srow) * ldb + scol;
    const unsigned short* Bg1 = B + (size_t)(bn + 64 + w * 16 + srow) * ldb + scol;
    unsigned short* la0 = &As[(w * 16) * 32];
    unsigned short* la1 = &As[(64 + w * 16) * 32];
    unsigned short* lb0 = &Bs[(w * 16) * 32];
    unsigned short* lb1 = &Bs[(64 + w * 16) * 32];

    const int fr = lane & 15;
    const int fk = (lane >> 4) * 8;

    for (int k0 = 0; k0 < K; k0 += 32) {
        __syncthreads();
        __builtin_amdgcn_global_load_lds((const AS1 void*)(Ag0 + k0), (AS3 void*)la0, 16, 0, 0);
        __builtin_amdgcn_global_load_lds((const AS1 void*)(Ag1 + k0), (AS3 void*)la1, 16, 0, 0);
        __builtin_amdgcn_global_load_lds((const AS1 void*)(Bg0 + k0), (AS3 void*)lb0, 16, 0, 0);
        __builtin_amdgcn_global_load_lds((const AS1 void*)(Bg1 + k0), (AS3 void*)lb1, 16, 0, 0);
        __syncthreads();

        bf16x8_t af[4], bfr[4];
#pragma unroll
        for (int i = 0; i < 4; ++i)
            af[i] = *(const bf16x8_t*)&As[(wm + i * 16 + fr) * 32 + fk];
#pragma unroll
        for (int j = 0; j < 4; ++j)
            bfr[j] = *(const bf16x8_t*)&Bs[(wn + j * 16 + fr) * 32 + fk];
#pragma unroll
        for (int i = 0; i < 4; ++i)
#pragma unroll
            for (int j = 0; j < 4; ++j)
                acc[i][j] = __builtin_amdgcn_mfma_f32_16x16x32_bf16(
                    af[i], bfr[j], acc[i][j], 0, 0, 0);
    }

    const int erow = (lane >> 4) * 4;
    const int ecol = lane & 15;
#pragma unroll
    for (int i = 0; i < 4; ++i) {
        int gr0 = bm + wm + i * 16 + erow;
#pragma unroll
        for (int j = 0; j < 4; ++j) {
            int gc = bn + wn + j * 16 + ecol;
#pragma unroll
            for (int r = 0; r < 4; ++r) {
                float v = acc[i][j][r];
                if (act == 1) {
                    float t = v + bias[gr0 + r];
                    v = (t > 20.f) ? t : log1pf(__expf(t));
                } else if (act == 2) {
                    v = v / (1.f + __expf(-v));
                }
                C[(size_t)(gr0 + r) * ldc + gc] = v;
            }
        }
    }
}

// ---------------------------------------------------------------------------
// causal depthwise conv (k=4) + bias + silu on [d][m] layout, bf16 output.
// ---------------------------------------------------------------------------
__global__ __launch_bounds__(256) void conv_silu_kernel(
    const float* __restrict__ xT,     // [2048][8192] fp32
    const float* __restrict__ w,      // [2048][4]
    const float* __restrict__ bias,   // [2048]
    unsigned short* __restrict__ xcT16) // [2048][8192] bf16
{
    int gid = blockIdx.x * blockDim.x + threadIdx.x;  // 0 .. 2048*2048-1
    int d = gid >> 11;
    int c4 = gid & 2047;
    int m0 = c4 * 4;
    int l0 = m0 & (L_SEQ - 1);

    const float* row = xT + (size_t)d * BL;
    float4 v = *(const float4*)(row + m0);
    float4 p;
    if (l0 == 0) { p.x = p.y = p.z = p.w = 0.f; }
    else         { p = *(const float4*)(row + m0 - 4); }

    float4 wv = ((const float4*)w)[d];
    float bb = bias[d];
    float e[4];
    e[0] = bb + wv.x * p.y + wv.y * p.z + wv.z * p.w + wv.w * v.x;
    e[1] = bb + wv.x * p.z + wv.y * p.w + wv.z * v.x + wv.w * v.y;
    e[2] = bb + wv.x * p.w + wv.y * v.x + wv.z * v.y + wv.w * v.z;
    e[3] = bb + wv.x * v.x + wv.y * v.y + wv.z * v.z + wv.w * v.w;
    ushort4 o;
    o.x = f2bf(e[0] / (1.f + __expf(-e[0])));
    o.y = f2bf(e[1] / (1.f + __expf(-e[1])));
    o.z = f2bf(e[2] / (1.f + __expf(-e[2])));
    o.w = f2bf(e[3] / (1.f + __expf(-e[3])));
    ((ushort4*)(xcT16 + (size_t)d * BL))[c4] = o;
}

// ---------------------------------------------------------------------------
// 32x32 tiled transposes (coalesced both sides)
// ---------------------------------------------------------------------------
__global__ __launch_bounds__(256) void transpose_f32_bf16(
    const float* __restrict__ in, int ldin,
    unsigned short* __restrict__ out, int ldout)
{
    __shared__ float tl[32][33];
    int r0 = blockIdx.y * 32, c0 = blockIdx.x * 32;
    int tx = threadIdx.x & 31, ty = threadIdx.x >> 5;
#pragma unroll
    for (int k = 0; k < 4; ++k)
        tl[ty + 8 * k][tx] = in[(size_t)(r0 + ty + 8 * k) * ldin + c0 + tx];
    __syncthreads();
#pragma unroll
    for (int k = 0; k < 4; ++k)
        out[(size_t)(c0 + ty + 8 * k) * ldout + r0 + tx] = f2bf(tl[tx][ty + 8 * k]);
}

__global__ __launch_bounds__(256) void transpose_bf16(
    const unsigned short* __restrict__ in, int ldin,
    unsigned short* __restrict__ out, int ldout)
{
    __shared__ unsigned short tl[32][33];
    int r0 = blockIdx.y * 32, c0 = blockIdx.x * 32;
    int tx = threadIdx.x & 31, ty = threadIdx.x >> 5;
#pragma unroll
    for (int k = 0; k < 4; ++k)
        tl[ty + 8 * k][tx] = in[(size_t)(r0 + ty + 8 * k) * ldin + c0 + tx];
    __syncthreads();
#pragma unroll
    for (int k = 0; k < 4; ++k)
        out[(size_t)(c0 + ty + 8 * k) * ldout + r0 + tx] = tl[tx][ty + 8 * k];
}

// ---------------------------------------------------------------------------
// Single-pass selective scan: ONE WAVE per (b,d) sequence.
//   4096 sequences -> 1024 blocks x 4 waves (each wave = its own d).
//   No pass1/pass2 redundancy (the old 8-wave chunked scan did 15/8x the
//   minimal recurrence work); occupancy drops to ~16 waves/CU which is
//   still >= 4 waves/SIMD -- enough to keep the VALU issue port saturated
//   (the kernel is VALU-bound: VALUBusy ~115%, HBM 3%).
//   dt/x staged per-wave into a private 512-step LDS slice, register-
//   prefetched one chunk ahead. B/C prefetched 8 steps ahead from global
//   (L2-resident: all 2048 d-waves of a batch share xdbl).
//   n-reduction: register fold-butterfly (verbatim from the verified
//   8-wave version): 3 fold stages (xor 32/16/8, blended sends) leaving
//   lane L with step t=(L>>3)&7 partial over n==L&7 (mod 8), then xor-4/2/1
//   butterfly. 10 shuffles / 8 steps, zero LDS for p.
//   exp folded to exp2: a = exp2(dt * (An*log2e)) -- saves 1 mul/step-lane.
//   b = blockIdx&1 so each XCD's round-robin share reads one batch's xdbl.
// ---------------------------------------------------------------------------
#define SCHUNK 512

__global__ __launch_bounds__(256, 4) void scan_seq_kernel(
    const float* __restrict__ dtT,           // [2048][8192] fp32
    const unsigned short* __restrict__ xcT16,// [2048][8192] bf16
    const float* __restrict__ xdbl,          // [8192+8][256] fp32 (B@+128, C@+192)
    float* __restrict__ zyT,                 // [2048][8192]: silu(z) in, y out
    const float* __restrict__ A_log,         // [2048][64]
    const float* __restrict__ Dp)            // [2048]
{
    __shared__ __align__(16) float s_dt[4][SCHUNK];           // 8 KB
    __shared__ __align__(16) unsigned short s_x[4][SCHUNK];   // 4 KB
    // 12 KB/block; 4 blocks/CU -> 16 waves/CU

    const int tid  = threadIdx.x;
    const int wid  = tid >> 6;
    const int lane = tid & 63;
    const int bi   = blockIdx.x;            // 0..1023
    const int b    = bi & 1;                // XCD-friendly: same-b per XCD
    const int d    = (bi >> 1) * 4 + wid;

    const size_t rowbase = (size_t)d * BL + (size_t)b * L_SEQ;
    const float An2 = -__expf(A_log[d * D_STATE + lane]) * 1.44269504f;
    const float Dd  = Dp[d];

    float* sdt = s_dt[wid];
    unsigned short* sx = s_x[wid];
    const float* dtrow = dtT + rowbase;
    const unsigned short* xrow = xcT16 + rowbase;
    float* zrow = zyT + rowbase;
    const int myt = (lane >> 3) & 7;        // step index this lane ends up with

    // prefetch chunk 0 (dt: 2x float4/lane = 512 floats; x: uint4/lane = 512 bf16)
    float4 pA = ((const float4*)dtrow)[lane];
    float4 pB = ((const float4*)dtrow)[lane + 64];
    uint4  pX = ((const uint4*)xrow)[lane];

    // rolling B/C prefetch (pad-safe past the end thanks to xdbl's 8-row pad)
    const float* bc = xdbl + ((size_t)b * L_SEQ) * 256 + DT_RANK + lane;
    float Bv[8], Cv[8];
#pragma unroll
    for (int t = 0; t < 8; ++t) { Bv[t] = bc[t * 256]; Cv[t] = bc[t * 256 + D_STATE]; }

    float h = 0.f;

    for (int c = 0; c < L_SEQ / SCHUNK; ++c) {
        // stage current chunk to this wave's private LDS slice (no barrier:
        // LDS ops are in-order within a wave)
        ((float4*)sdt)[lane]      = pA;
        ((float4*)sdt)[lane + 64] = pB;
        ((uint4*)sx)[lane]        = pX;
        if (c < L_SEQ / SCHUNK - 1) {       // register-prefetch next chunk
            pA = ((const float4*)(dtrow + (c + 1) * SCHUNK))[lane];
            pB = ((const float4*)(dtrow + (c + 1) * SCHUNK))[lane + 64];
            pX = ((const uint4*)(xrow + (c + 1) * SCHUNK))[lane];
        }

        for (int g = 0; g < SCHUNK; g += 8) {
            float Bn[8], Cn[8];
            const float* bn_ = bc + 8 * 256;
#pragma unroll
            for (int t = 0; t < 8; ++t) {                 // prefetch next group
                Bn[t] = bn_[t * 256];
                Cn[t] = bn_[t * 256 + D_STATE];
            }

            float4 dta = *(const float4*)&sdt[g];
            float4 dtb = *(const float4*)&sdt[g + 4];
            uint4 xr = *(const uint4*)&sx[g];
            float dt8[8] = {dta.x, dta.y, dta.z, dta.w, dtb.x, dtb.y, dtb.z, dtb.w};
            float xf[8];
            xf[0] = __uint_as_float(xr.x << 16); xf[1] = __uint_as_float(xr.x & 0xffff0000u);
            xf[2] = __uint_as_float(xr.y << 16); xf[3] = __uint_as_float(xr.y & 0xffff0000u);
            xf[4] = __uint_as_float(xr.z << 16); xf[5] = __uint_as_float(xr.z & 0xffff0000u);
            xf[6] = __uint_as_float(xr.w << 16); xf[7] = __uint_as_float(xr.w & 0xffff0000u);

            float pr[8];
#pragma unroll
            for (int t = 0; t < 8; ++t) {
                float a = __builtin_amdgcn_exp2f(dt8[t] * An2);
                h = fmaf(h, a, (dt8[t] * xf[t]) * Bv[t]);
                pr[t] = h * Cv[t];
            }

            // fold stage 1 (xor 32): 8 values -> 4
#pragma unroll
            for (int t = 0; t < 4; ++t) {
                float send = (lane & 32) ? pr[t] : pr[t + 4];
                float recv = __shfl_xor(send, 32);
                pr[t] = ((lane & 32) ? pr[t + 4] : pr[t]) + recv;
            }
            // fold stage 2 (xor 16): 4 -> 2
#pragma unroll
            for (int t = 0; t < 2; ++t) {
                float send = (lane & 16) ? pr[t] : pr[t + 2];
                float recv = __shfl_xor(send, 16);
                pr[t] = ((lane & 16) ? pr[t + 2] : pr[t]) + recv;
            }
            // fold stage 3 (xor 8): 2 -> 1  (lane now holds step myt, n==lane&7 mod 8)
            {
                float send = (lane & 8) ? pr[0] : pr[1];
                float recv = __shfl_xor(send, 8);
                pr[0] = ((lane & 8) ? pr[1] : pr[0]) + recv;
            }
            // butterfly over the 8 n-residues
            pr[0] += __shfl_xor(pr[0], 4);
            pr[0] += __shfl_xor(pr[0], 2);
            pr[0] += __shfl_xor(pr[0], 1);

            if ((lane & 7) == 0) {   // one lane per step group
                int t0 = g + myt;
                float xv = bf2f(sx[t0]);
                float zv = zrow[c * SCHUNK + t0];
                zrow[c * SCHUNK + t0] = fmaf(Dd, xv, pr[0]) * zv;
            }

#pragma unroll
            for (int t = 0; t < 8; ++t) { Bv[t] = Bn[t]; Cv[t] = Cn[t]; }
            bc += 8 * 256;
        }
    }
}

// ---------------------------------------------------------------------------
extern "C" void kernel_launch(void* const* d_in, const int* in_sizes, int n_in,
                              void* d_out, int out_size, void* d_ws, size_t ws_size,
                              hipStream_t stream)
{
    const float* hs        = (const float*)d_in[0];  // [8192][1024]
    const float* in_proj_w = (const float*)d_in[1];  // [4096][1024]
    const float* conv_w    = (const float*)d_in[2];  // [2048][4]
    const float* conv_b    = (const float*)d_in[3];  // [2048]
    const float* x_proj_w  = (const float*)d_in[4];  // [256][2048]
    const float* dt_proj_w = (const float*)d_in[5];  // [2048][128]
    const float* dt_proj_b = (const float*)d_in[6];  // [2048]
    const float* A_log     = (const float*)d_in[7];  // [2048][64]
    const float* Dp        = (const float*)d_in[8];  // [2048]
    const float* out_proj_w= (const float*)d_in[9];  // [1024][2048]
    float* out = (float*)d_out;                      // [8192][1024]

    // workspace map (MiB offsets; peak ~177.5 MiB):
    //  S0 @0   : xT fp32 (64) -> xc16 bf16 (32) @0 -> dtT fp32 (64) @0
    //  S1 @64  : zT fp32 (64)  (scan writes y in place)
    //  S2 @128 : W1_16 (8)@128 + hs16 (16)@136 -> xcT16 bf16 (32)@128 -> y16 (32)@128
    //  tail    : xdbl fp32 (8+pad)@160, xdbl16 (2)@169, Wx16 (1)@171,
    //            Wdt16 (.5)@172, Wo16 (4)@173  (end 177)
    char* ws = (char*)d_ws;
    const size_t MiB = 1024 * 1024;
    float*          xT    = (float*)(ws);
    unsigned short* xc16  = (unsigned short*)(ws);
    float*          dtT   = (float*)(ws);
    float*          zT    = (float*)(ws + 64 * MiB);
    unsigned short* W1_16 = (unsigned short*)(ws + 128 * MiB);
    unsigned short* hs16  = (unsigned short*)(ws + 136 * MiB);
    unsigned short* xcT16 = (unsigned short*)(ws + 128 * MiB);
    unsigned short* y16   = (unsigned short*)(ws + 128 * MiB);
    float*          xdbl  = (float*)(ws + 160 * MiB);   // 8 MiB + 8-row pad
    unsigned short* xdbl16= (unsigned short*)(ws + 169 * MiB);
    unsigned short* Wx16  = (unsigned short*)(ws + 171 * MiB);
    unsigned short* Wdt16 = (unsigned short*)(ws + 172 * MiB);
    unsigned short* Wo16  = (unsigned short*)(ws + 173 * MiB);

    dim3 blk(256);

    // bf16 conversions
    cvt_f32_bf16<<<8192, blk, 0, stream>>>(hs, hs16, 2097152);
    cvt_f32_bf16<<<4096, blk, 0, stream>>>(in_proj_w, W1_16, 1048576);
    cvt_f32_bf16<<<512, blk, 0, stream>>>(x_proj_w, Wx16, 131072);
    cvt_f32_bf16<<<256, blk, 0, stream>>>(dt_proj_w, Wdt16, 65536);
    cvt_f32_bf16<<<2048, blk, 0, stream>>>(out_proj_w, Wo16, 524288);

    // 1) xT[d][m] = W1x . hs^T   (M=2048, N=8192, K=1024)
    gemm_bf16<<<dim3(64, 16), blk, 0, stream>>>(
        W1_16, D_MODEL, hs16, D_MODEL, xT, BL, D_MODEL, nullptr, 0);

    // 2) zT[d][m] = silu(W1z . hs^T)
    gemm_bf16<<<dim3(64, 16), blk, 0, stream>>>(
        W1_16 + (size_t)D_INNER * D_MODEL, D_MODEL, hs16, D_MODEL,
        zT, BL, D_MODEL, nullptr, 2);

    // 3) xcT16 = bf16(silu(conv(xT) + b))
    conv_silu_kernel<<<(D_INNER * (BL / 4)) / 256, blk, 0, stream>>>(
        xT, conv_w, conv_b, xcT16);

    // 4) xc16[m][d] = transpose(xcT16)
    transpose_bf16<<<dim3(BL / 32, D_INNER / 32), blk, 0, stream>>>(
        xcT16, BL, xc16, D_INNER);

    // 5) xdbl[m][256] = xc . x_proj^T   (M=8192, N=256, K=2048)
    gemm_bf16<<<dim3(2, 64), blk, 0, stream>>>(
        xc16, D_INNER, Wx16, D_INNER, xdbl, 256, D_INNER, nullptr, 0);

    // 6) xdbl16 = bf16(xdbl[:, :128])
    cvt_dtpart<<<1024, blk, 0, stream>>>(xdbl, xdbl16);

    // 7) dtT[d][m] = softplus(Wdt . xdbl_dt^T + b[d])  (M=2048, N=8192, K=128)
    gemm_bf16<<<dim3(64, 16), blk, 0, stream>>>(
        Wdt16, DT_RANK, xdbl16, DT_RANK, dtT, BL, DT_RANK, dt_proj_b, 1);

    // 8) single-pass scan: 1 wave per (b,d), y in place over zT
    scan_seq_kernel<<<(B_SZ * D_INNER) / 4, blk, 0, stream>>>(
        dtT, xcT16, xdbl, zT, A_log, Dp);

    // 9) y16[m][d] = bf16(transpose(zT))
    transpose_f32_bf16<<<dim3(BL / 32, D_INNER / 32), blk, 0, stream>>>(
        zT, BL, y16, D_INNER);

    // 10) out = y . out_proj^T   (M=8192, N=1024, K=2048)
    gemm_bf16<<<dim3(8, 64), blk, 0, stream>>>(
        y16, D_INNER, Wo16, D_INNER, out, D_MODEL, D_INNER, nullptr, 0);
}

// Round 3
// 913.818 us; speedup vs baseline: 1.2038x; 1.0713x over previous
//
#include <hip/hip_runtime.h>
#include <math.h>

// Problem constants (fixed by the reference)
#define B_SZ 2
#define L_SEQ 4096
#define D_MODEL 1024
#define D_INNER 2048
#define D_STATE 64
#define DT_RANK 128
#define BL (B_SZ * L_SEQ)          // 8192 tokens

#define AS1 __attribute__((address_space(1)))
#define AS3 __attribute__((address_space(3)))

typedef __attribute__((ext_vector_type(8))) short bf16x8_t;  // 8 bf16 = 4 VGPRs
typedef __attribute__((ext_vector_type(4))) float f32x4_t;

__device__ __forceinline__ unsigned short f2bf(float f) {
    unsigned int u = __float_as_uint(f);
    u = (u + 0x7FFFu + ((u >> 16) & 1u)) >> 16;   // RNE
    return (unsigned short)u;
}
__device__ __forceinline__ float bf2f(unsigned short h) {
    return __uint_as_float(((unsigned int)h) << 16);
}

// ---------------------------------------------------------------------------
// fp32 -> bf16 bulk convert (n4 = count of float4 groups)
// ---------------------------------------------------------------------------
__global__ __launch_bounds__(256) void cvt_f32_bf16(
    const float* __restrict__ in, unsigned short* __restrict__ out, int n4)
{
    int i = blockIdx.x * 256 + threadIdx.x;
    if (i >= n4) return;
    float4 v = ((const float4*)in)[i];
    ushort4 o;
    o.x = f2bf(v.x); o.y = f2bf(v.y); o.z = f2bf(v.z); o.w = f2bf(v.w);
    ((ushort4*)out)[i] = o;
}

// xdbl[:, :128] (fp32, row stride 256) -> packed bf16 [8192][128]
__global__ __launch_bounds__(256) void cvt_dtpart(
    const float* __restrict__ xdbl, unsigned short* __restrict__ out)
{
    int i = blockIdx.x * 256 + threadIdx.x;   // 0 .. 8192*32-1
    int m = i >> 5, c = i & 31;
    float4 v = *(const float4*)(xdbl + (size_t)m * 256 + c * 4);
    ushort4 o;
    o.x = f2bf(v.x); o.y = f2bf(v.y); o.z = f2bf(v.z); o.w = f2bf(v.w);
    ((ushort4*)(out))[(size_t)m * 32 + c] = o;
}

// ---------------------------------------------------------------------------
// bf16 MFMA GEMM: C[m][n] = act( sum_k A[m][k]*B[n][k] [+ bias[m]] )
// A: M x K bf16 row-major (lda), B: N x K bf16 row-major (ldb), C fp32 (ldc).
// act: 0 none, 1 softplus with bias indexed by ROW m, 2 silu.
// Tile 128x128, BK=32, 256 threads = 4 waves (2x2 of 64x64 per wave).
// ---------------------------------------------------------------------------
__global__ __launch_bounds__(256) void gemm_bf16(
    const unsigned short* __restrict__ A, int lda,
    const unsigned short* __restrict__ B, int ldb,
    float* __restrict__ C, int ldc, int K,
    const float* __restrict__ bias, int act)
{
    __shared__ unsigned short As[128 * 32];   // [row][k] linear, no pad
    __shared__ unsigned short Bs[128 * 32];

    const int tid = threadIdx.x;
    const int w = tid >> 6, lane = tid & 63;
    const int bm = blockIdx.y * 128, bn = blockIdx.x * 128;
    const int wm = (w & 1) * 64, wn = (w >> 1) * 64;

    f32x4_t acc[4][4];
#pragma unroll
    for (int i = 0; i < 4; ++i)
#pragma unroll
        for (int j = 0; j < 4; ++j) acc[i][j] = (f32x4_t){0.f, 0.f, 0.f, 0.f};

    const int srow = lane >> 2;
    const int scol = (lane & 3) * 8;
    const unsigned short* Ag0 = A + (size_t)(bm + w * 16 + srow) * lda + scol;
    const unsigned short* Ag1 = A + (size_t)(bm + 64 + w * 16 + srow) * lda + scol;
    const unsigned short* Bg0 = B + (size_t)(bn + w * 16 + srow) * ldb + scol;
    const unsigned short* Bg1 = B + (size_t)(bn + 64 + w * 16 + srow) * ldb + scol;
    unsigned short* la0 = &As[(w * 16) * 32];
    unsigned short* la1 = &As[(64 + w * 16) * 32];
    unsigned short* lb0 = &Bs[(w * 16) * 32];
    unsigned short* lb1 = &Bs[(64 + w * 16) * 32];

    const int fr = lane & 15;
    const int fk = (lane >> 4) * 8;

    for (int k0 = 0; k0 < K; k0 += 32) {
        __syncthreads();
        __builtin_amdgcn_global_load_lds((const AS1 void*)(Ag0 + k0), (AS3 void*)la0, 16, 0, 0);
        __builtin_amdgcn_global_load_lds((const AS1 void*)(Ag1 + k0), (AS3 void*)la1, 16, 0, 0);
        __builtin_amdgcn_global_load_lds((const AS1 void*)(Bg0 + k0), (AS3 void*)lb0, 16, 0, 0);
        __builtin_amdgcn_global_load_lds((const AS1 void*)(Bg1 + k0), (AS3 void*)lb1, 16, 0, 0);
        __syncthreads();

        bf16x8_t af[4], bfr[4];
#pragma unroll
        for (int i = 0; i < 4; ++i)
            af[i] = *(const bf16x8_t*)&As[(wm + i * 16 + fr) * 32 + fk];
#pragma unroll
        for (int j = 0; j < 4; ++j)
            bfr[j] = *(const bf16x8_t*)&Bs[(wn + j * 16 + fr) * 32 + fk];
#pragma unroll
        for (int i = 0; i < 4; ++i)
#pragma unroll
            for (int j = 0; j < 4; ++j)
                acc[i][j] = __builtin_amdgcn_mfma_f32_16x16x32_bf16(
                    af[i], bfr[j], acc[i][j], 0, 0, 0);
    }

    const int erow = (lane >> 4) * 4;
    const int ecol = lane & 15;
#pragma unroll
    for (int i = 0; i < 4; ++i) {
        int gr0 = bm + wm + i * 16 + erow;
#pragma unroll
        for (int j = 0; j < 4; ++j) {
            int gc = bn + wn + j * 16 + ecol;
#pragma unroll
            for (int r = 0; r < 4; ++r) {
                float v = acc[i][j][r];
                if (act == 1) {
                    float t = v + bias[gr0 + r];
                    v = (t > 20.f) ? t : log1pf(__expf(t));
                } else if (act == 2) {
                    v = v / (1.f + __expf(-v));
                }
                C[(size_t)(gr0 + r) * ldc + gc] = v;
            }
        }
    }
}

// ---------------------------------------------------------------------------
// causal depthwise conv (k=4) + bias + silu on [d][m] layout, bf16 output.
// ---------------------------------------------------------------------------
__global__ __launch_bounds__(256) void conv_silu_kernel(
    const float* __restrict__ xT,     // [2048][8192] fp32
    const float* __restrict__ w,      // [2048][4]
    const float* __restrict__ bias,   // [2048]
    unsigned short* __restrict__ xcT16) // [2048][8192] bf16
{
    int gid = blockIdx.x * blockDim.x + threadIdx.x;  // 0 .. 2048*2048-1
    int d = gid >> 11;
    int c4 = gid & 2047;
    int m0 = c4 * 4;
    int l0 = m0 & (L_SEQ - 1);

    const float* row = xT + (size_t)d * BL;
    float4 v = *(const float4*)(row + m0);
    float4 p;
    if (l0 == 0) { p.x = p.y = p.z = p.w = 0.f; }
    else         { p = *(const float4*)(row + m0 - 4); }

    float4 wv = ((const float4*)w)[d];
    float bb = bias[d];
    float e[4];
    e[0] = bb + wv.x * p.y + wv.y * p.z + wv.z * p.w + wv.w * v.x;
    e[1] = bb + wv.x * p.z + wv.y * p.w + wv.z * v.x + wv.w * v.y;
    e[2] = bb + wv.x * p.w + wv.y * v.x + wv.z * v.y + wv.w * v.z;
    e[3] = bb + wv.x * v.x + wv.y * v.y + wv.z * v.z + wv.w * v.w;
    ushort4 o;
    o.x = f2bf(e[0] / (1.f + __expf(-e[0])));
    o.y = f2bf(e[1] / (1.f + __expf(-e[1])));
    o.z = f2bf(e[2] / (1.f + __expf(-e[2])));
    o.w = f2bf(e[3] / (1.f + __expf(-e[3])));
    ((ushort4*)(xcT16 + (size_t)d * BL))[c4] = o;
}

// ---------------------------------------------------------------------------
// 32x32 tiled transposes (coalesced both sides)
// ---------------------------------------------------------------------------
__global__ __launch_bounds__(256) void transpose_f32_bf16(
    const float* __restrict__ in, int ldin,
    unsigned short* __restrict__ out, int ldout)
{
    __shared__ float tl[32][33];
    int r0 = blockIdx.y * 32, c0 = blockIdx.x * 32;
    int tx = threadIdx.x & 31, ty = threadIdx.x >> 5;
#pragma unroll
    for (int k = 0; k < 4; ++k)
        tl[ty + 8 * k][tx] = in[(size_t)(r0 + ty + 8 * k) * ldin + c0 + tx];
    __syncthreads();
#pragma unroll
    for (int k = 0; k < 4; ++k)
        out[(size_t)(c0 + ty + 8 * k) * ldout + r0 + tx] = f2bf(tl[tx][ty + 8 * k]);
}

__global__ __launch_bounds__(256) void transpose_bf16(
    const unsigned short* __restrict__ in, int ldin,
    unsigned short* __restrict__ out, int ldout)
{
    __shared__ unsigned short tl[32][33];
    int r0 = blockIdx.y * 32, c0 = blockIdx.x * 32;
    int tx = threadIdx.x & 31, ty = threadIdx.x >> 5;
#pragma unroll
    for (int k = 0; k < 4; ++k)
        tl[ty + 8 * k][tx] = in[(size_t)(r0 + ty + 8 * k) * ldin + c0 + tx];
    __syncthreads();
#pragma unroll
    for (int k = 0; k < 4; ++k)
        out[(size_t)(c0 + ty + 8 * k) * ldout + r0 + tx] = tl[tx][ty + 8 * k];
}

// ---------------------------------------------------------------------------
// Single-pass selective scan: ONE WAVE per (b,d) sequence.
//   R2 post-mortem: VALUBusy fell to 76% (dependent z global read + depth-6
//   shuffle chain every 8 steps + Bv/Cv register copies). R3 changes:
//     - z staged into LDS per chunk (register-prefetched) -> no dependent
//       global read in the inner loop.
//     - 16-step fold network (one more blended-send stage): 17 shuffles /
//       16 steps (was 20), half the chain frequency, 16-step B/C prefetch
//       distance (~1000 cy of latency cover).
//     - ping-pong B/C register sets (two GROUP16 bodies per iter): zero
//       v_mov copies.
//   Reduction layout: after xor32/xor16/xor8/xor4 folds, lane L holds step
//   (L>>2)&15 partial over n == L&3 (mod 4); xor2/xor1 butterfly completes.
//   Writer lanes: L&3 == 0 (16 lanes, 16 consecutive floats).
// ---------------------------------------------------------------------------
#define SCHUNK 512

#define GROUP16(BC, CC, BN, CN, GG)                                          \
{                                                                            \
    const float* bn_ = bc + 16 * 256;                                        \
    _Pragma("unroll")                                                        \
    for (int t = 0; t < 16; ++t) {                                           \
        BN[t] = bn_[t * 256];                                                \
        CN[t] = bn_[t * 256 + D_STATE];                                      \
    }                                                                        \
    float4 dta = *(const float4*)&sdt[(GG)];                                 \
    float4 dtb = *(const float4*)&sdt[(GG) + 4];                             \
    float4 dtc = *(const float4*)&sdt[(GG) + 8];                             \
    float4 dtd = *(const float4*)&sdt[(GG) + 12];                            \
    uint4 xr0 = *(const uint4*)&sx[(GG)];                                    \
    uint4 xr1 = *(const uint4*)&sx[(GG) + 8];                                \
    float dt16[16] = {dta.x, dta.y, dta.z, dta.w, dtb.x, dtb.y, dtb.z, dtb.w,\
                      dtc.x, dtc.y, dtc.z, dtc.w, dtd.x, dtd.y, dtd.z, dtd.w};\
    float xf[16];                                                            \
    xf[0]  = __uint_as_float(xr0.x << 16); xf[1]  = __uint_as_float(xr0.x & 0xffff0000u); \
    xf[2]  = __uint_as_float(xr0.y << 16); xf[3]  = __uint_as_float(xr0.y & 0xffff0000u); \
    xf[4]  = __uint_as_float(xr0.z << 16); xf[5]  = __uint_as_float(xr0.z & 0xffff0000u); \
    xf[6]  = __uint_as_float(xr0.w << 16); xf[7]  = __uint_as_float(xr0.w & 0xffff0000u); \
    xf[8]  = __uint_as_float(xr1.x << 16); xf[9]  = __uint_as_float(xr1.x & 0xffff0000u); \
    xf[10] = __uint_as_float(xr1.y << 16); xf[11] = __uint_as_float(xr1.y & 0xffff0000u); \
    xf[12] = __uint_as_float(xr1.z << 16); xf[13] = __uint_as_float(xr1.z & 0xffff0000u); \
    xf[14] = __uint_as_float(xr1.w << 16); xf[15] = __uint_as_float(xr1.w & 0xffff0000u); \
    float pr[16];                                                            \
    _Pragma("unroll")                                                        \
    for (int t = 0; t < 16; ++t) {                                           \
        float a = __builtin_amdgcn_exp2f(dt16[t] * An2);                     \
        h = fmaf(h, a, (dt16[t] * xf[t]) * BC[t]);                           \
        pr[t] = h * CC[t];                                                   \
    }                                                                        \
    _Pragma("unroll")                                                        \
    for (int t = 0; t < 8; ++t) {       /* fold xor32: 16 -> 8 */            \
        float send = (lane & 32) ? pr[t] : pr[t + 8];                        \
        float recv = __shfl_xor(send, 32);                                   \
        pr[t] = ((lane & 32) ? pr[t + 8] : pr[t]) + recv;                    \
    }                                                                        \
    _Pragma("unroll")                                                        \
    for (int t = 0; t < 4; ++t) {       /* fold xor16: 8 -> 4 */             \
        float send = (lane & 16) ? pr[t] : pr[t + 4];                        \
        float recv = __shfl_xor(send, 16);                                   \
        pr[t] = ((lane & 16) ? pr[t + 4] : pr[t]) + recv;                    \
    }                                                                        \
    _Pragma("unroll")                                                        \
    for (int t = 0; t < 2; ++t) {       /* fold xor8: 4 -> 2 */              \
        float send = (lane & 8) ? pr[t] : pr[t + 2];                         \
        float recv = __shfl_xor(send, 8);                                    \
        pr[t] = ((lane & 8) ? pr[t + 2] : pr[t]) + recv;                     \
    }                                                                        \
    {                                   /* fold xor4: 2 -> 1 */              \
        float send = (lane & 4) ? pr[0] : pr[1];                             \
        float recv = __shfl_xor(send, 4);                                    \
        pr[0] = ((lane & 4) ? pr[1] : pr[0]) + recv;                         \
    }                                                                        \
    pr[0] += __shfl_xor(pr[0], 2);      /* butterfly over 4 n-residues */    \
    pr[0] += __shfl_xor(pr[0], 1);                                           \
    if ((lane & 3) == 0) {              /* 16 writer lanes, step (lane>>2)&15 */ \
        int t0 = (GG) + myt16;                                               \
        float xv = bf2f(sx[t0]);                                             \
        float zv = sz[t0];                                                   \
        zrow[cbase + t0] = fmaf(Dd, xv, pr[0]) * zv;                         \
    }                                                                        \
    bc += 16 * 256;                                                          \
}

__global__ __launch_bounds__(256, 4) void scan_seq_kernel(
    const float* __restrict__ dtT,           // [2048][8192] fp32
    const unsigned short* __restrict__ xcT16,// [2048][8192] bf16
    const float* __restrict__ xdbl,          // [8192+16][256] fp32 (B@+128, C@+192)
    float* __restrict__ zyT,                 // [2048][8192]: silu(z) in, y out
    const float* __restrict__ A_log,         // [2048][64]
    const float* __restrict__ Dp)            // [2048]
{
    __shared__ __align__(16) float s_dt[4][SCHUNK];           // 8 KB
    __shared__ __align__(16) unsigned short s_x[4][SCHUNK];   // 4 KB
    __shared__ __align__(16) float s_z[4][SCHUNK];            // 8 KB
    // 20 KB/block; grid gives 4 blocks/CU (16 waves/CU)

    const int tid  = threadIdx.x;
    const int wid  = tid >> 6;
    const int lane = tid & 63;
    const int bi   = blockIdx.x;            // 0..1023
    const int b    = bi & 1;                // XCD-friendly: same-b per XCD
    const int d    = (bi >> 1) * 4 + wid;

    const size_t rowbase = (size_t)d * BL + (size_t)b * L_SEQ;
    const float An2 = -__expf(A_log[d * D_STATE + lane]) * 1.44269504f;
    const float Dd  = Dp[d];

    float* sdt = s_dt[wid];
    unsigned short* sx = s_x[wid];
    float* sz = s_z[wid];
    const float* dtrow = dtT + rowbase;
    const unsigned short* xrow = xcT16 + rowbase;
    float* zrow = zyT + rowbase;
    const int myt16 = (lane >> 2) & 15;     // step index this lane ends up with

    // prefetch chunk 0 (dt/z: 2x float4/lane = 512 f32; x: uint4/lane = 512 bf16)
    float4 pA = ((const float4*)dtrow)[lane];
    float4 pB = ((const float4*)dtrow)[lane + 64];
    uint4  pX = ((const uint4*)xrow)[lane];
    float4 pZ0 = ((const float4*)zrow)[lane];
    float4 pZ1 = ((const float4*)zrow)[lane + 64];

    // rolling B/C prefetch, ping-pong sets (pad-safe past the end: xdbl has
    // >=16 rows of slack before the next workspace buffer)
    const float* bc = xdbl + ((size_t)b * L_SEQ) * 256 + DT_RANK + lane;
    float Bv0[16], Cv0[16], Bv1[16], Cv1[16];
#pragma unroll
    for (int t = 0; t < 16; ++t) { Bv0[t] = bc[t * 256]; Cv0[t] = bc[t * 256 + D_STATE]; }

    float h = 0.f;

    for (int c = 0; c < L_SEQ / SCHUNK; ++c) {
        // stage current chunk to this wave's private LDS slice (no barrier:
        // intra-wave LDS write->read ordering via lgkmcnt)
        ((float4*)sdt)[lane]      = pA;
        ((float4*)sdt)[lane + 64] = pB;
        ((uint4*)sx)[lane]        = pX;
        ((float4*)sz)[lane]       = pZ0;
        ((float4*)sz)[lane + 64]  = pZ1;
        if (c < L_SEQ / SCHUNK - 1) {       // register-prefetch next chunk
            pA  = ((const float4*)(dtrow + (c + 1) * SCHUNK))[lane];
            pB  = ((const float4*)(dtrow + (c + 1) * SCHUNK))[lane + 64];
            pX  = ((const uint4*)(xrow + (c + 1) * SCHUNK))[lane];
            pZ0 = ((const float4*)(zrow + (c + 1) * SCHUNK))[lane];
            pZ1 = ((const float4*)(zrow + (c + 1) * SCHUNK))[lane + 64];
        }
        const int cbase = c * SCHUNK;

        for (int g = 0; g < SCHUNK; g += 32) {
            GROUP16(Bv0, Cv0, Bv1, Cv1, g);
            GROUP16(Bv1, Cv1, Bv0, Cv0, g + 16);
        }
    }
}

// ---------------------------------------------------------------------------
extern "C" void kernel_launch(void* const* d_in, const int* in_sizes, int n_in,
                              void* d_out, int out_size, void* d_ws, size_t ws_size,
                              hipStream_t stream)
{
    const float* hs        = (const float*)d_in[0];  // [8192][1024]
    const float* in_proj_w = (const float*)d_in[1];  // [4096][1024]
    const float* conv_w    = (const float*)d_in[2];  // [2048][4]
    const float* conv_b    = (const float*)d_in[3];  // [2048]
    const float* x_proj_w  = (const float*)d_in[4];  // [256][2048]
    const float* dt_proj_w = (const float*)d_in[5];  // [2048][128]
    const float* dt_proj_b = (const float*)d_in[6];  // [2048]
    const float* A_log     = (const float*)d_in[7];  // [2048][64]
    const float* Dp        = (const float*)d_in[8];  // [2048]
    const float* out_proj_w= (const float*)d_in[9];  // [1024][2048]
    float* out = (float*)d_out;                      // [8192][1024]

    // workspace map (MiB offsets; peak ~177.5 MiB):
    //  S0 @0   : xT fp32 (64) -> xc16 bf16 (32) @0 -> dtT fp32 (64) @0
    //  S1 @64  : zT fp32 (64)  (scan writes y in place)
    //  S2 @128 : W1_16 (8)@128 + hs16 (16)@136 -> xcT16 bf16 (32)@128 -> y16 (32)@128
    //  tail    : xdbl fp32 (8+pad)@160, xdbl16 (2)@169, Wx16 (1)@171,
    //            Wdt16 (.5)@172, Wo16 (4)@173  (end 177)
    char* ws = (char*)d_ws;
    const size_t MiB = 1024 * 1024;
    float*          xT    = (float*)(ws);
    unsigned short* xc16  = (unsigned short*)(ws);
    float*          dtT   = (float*)(ws);
    float*          zT    = (float*)(ws + 64 * MiB);
    unsigned short* W1_16 = (unsigned short*)(ws + 128 * MiB);
    unsigned short* hs16  = (unsigned short*)(ws + 136 * MiB);
    unsigned short* xcT16 = (unsigned short*)(ws + 128 * MiB);
    unsigned short* y16   = (unsigned short*)(ws + 128 * MiB);
    float*          xdbl  = (float*)(ws + 160 * MiB);   // 8 MiB + >=16-row pad
    unsigned short* xdbl16= (unsigned short*)(ws + 169 * MiB);
    unsigned short* Wx16  = (unsigned short*)(ws + 171 * MiB);
    unsigned short* Wdt16 = (unsigned short*)(ws + 172 * MiB);
    unsigned short* Wo16  = (unsigned short*)(ws + 173 * MiB);

    dim3 blk(256);

    // bf16 conversions
    cvt_f32_bf16<<<8192, blk, 0, stream>>>(hs, hs16, 2097152);
    cvt_f32_bf16<<<4096, blk, 0, stream>>>(in_proj_w, W1_16, 1048576);
    cvt_f32_bf16<<<512, blk, 0, stream>>>(x_proj_w, Wx16, 131072);
    cvt_f32_bf16<<<256, blk, 0, stream>>>(dt_proj_w, Wdt16, 65536);
    cvt_f32_bf16<<<2048, blk, 0, stream>>>(out_proj_w, Wo16, 524288);

    // 1) xT[d][m] = W1x . hs^T   (M=2048, N=8192, K=1024)
    gemm_bf16<<<dim3(64, 16), blk, 0, stream>>>(
        W1_16, D_MODEL, hs16, D_MODEL, xT, BL, D_MODEL, nullptr, 0);

    // 2) zT[d][m] = silu(W1z . hs^T)
    gemm_bf16<<<dim3(64, 16), blk, 0, stream>>>(
        W1_16 + (size_t)D_INNER * D_MODEL, D_MODEL, hs16, D_MODEL,
        zT, BL, D_MODEL, nullptr, 2);

    // 3) xcT16 = bf16(silu(conv(xT) + b))
    conv_silu_kernel<<<(D_INNER * (BL / 4)) / 256, blk, 0, stream>>>(
        xT, conv_w, conv_b, xcT16);

    // 4) xc16[m][d] = transpose(xcT16)
    transpose_bf16<<<dim3(BL / 32, D_INNER / 32), blk, 0, stream>>>(
        xcT16, BL, xc16, D_INNER);

    // 5) xdbl[m][256] = xc . x_proj^T   (M=8192, N=256, K=2048)
    gemm_bf16<<<dim3(2, 64), blk, 0, stream>>>(
        xc16, D_INNER, Wx16, D_INNER, xdbl, 256, D_INNER, nullptr, 0);

    // 6) xdbl16 = bf16(xdbl[:, :128])
    cvt_dtpart<<<1024, blk, 0, stream>>>(xdbl, xdbl16);

    // 7) dtT[d][m] = softplus(Wdt . xdbl_dt^T + b[d])  (M=2048, N=8192, K=128)
    gemm_bf16<<<dim3(64, 16), blk, 0, stream>>>(
        Wdt16, DT_RANK, xdbl16, DT_RANK, dtT, BL, DT_RANK, dt_proj_b, 1);

    // 8) single-pass scan: 1 wave per (b,d), y in place over zT
    scan_seq_kernel<<<(B_SZ * D_INNER) / 4, blk, 0, stream>>>(
        dtT, xcT16, xdbl, zT, A_log, Dp);

    // 9) y16[m][d] = bf16(transpose(zT))
    transpose_f32_bf16<<<dim3(BL / 32, D_INNER / 32), blk, 0, stream>>>(
        zT, BL, y16, D_INNER);

    // 10) out = y . out_proj^T   (M=8192, N=1024, K=2048)
    gemm_bf16<<<dim3(8, 64), blk, 0, stream>>>(
        y16, D_INNER, Wo16, D_INNER, out, D_MODEL, D_INNER, nullptr, 0);
}